// Round 6
// baseline (36990.683 us; speedup 1.0000x reference)
//
#include <hip/hip_runtime.h>
#include <stdint.h>

typedef unsigned long long u64;

#define Bq 64
#define Tq 256
#define Hq 512
#define Eq 512
#define Vq 32000

__device__ __forceinline__ float sigmoid_f(float x) { return 1.0f / (1.0f + expf(-x)); }

__device__ __forceinline__ unsigned f2sortable(float f) {
    unsigned u = __float_as_uint(f);
    return (u & 0x80000000u) ? ~u : (u | 0x80000000u);
}

// async global->LDS, 16B per lane; LDS dest is wave-uniform base + lane*16
__device__ __forceinline__ void gl_lds16(const float* g, float* l) {
    __builtin_amdgcn_global_load_lds(
        (const __attribute__((address_space(1))) void*)g,
        (__attribute__((address_space(3))) void*)l, 16, 0, 0);
}

// State layout "stateT": element (k, b) stored at (k>>2)*256 + b*4 + (k&3).
// float4 at word (kq*256 + b*4) == h[b][4kq..4kq+3]  (per-(b,kq) contiguous).

#define DOT4(acc, a, wv) \
    acc = fmaf((a).w, (wv).w, fmaf((a).z, (wv).z, fmaf((a).y, (wv).y, fmaf((a).x, (wv).x, (acc)))))

// ---------------------------------------------------------------------------
// Software grid barrier, MONOTONIC with LAUNCH-RELATIVE targets (no resets,
// no cross-launch assumptions).
//   - Counters in __device__ globals (zero .bss at load), NEVER reset.
//   - At kernel entry each block captures base_leaf = leaf & ~63,
//     base_root = root & ~7. Exact: before MY arrival, my leaf can gain at
//     most 63 in-launch arrivals (the 64th is me) and root at most 7 (my
//     leaf can't complete without me), so flooring to the per-launch
//     multiples (64*768 and 8*768 per launch) recovers the launch base.
//   - Barrier k: arrive leaf(bid&7); winner (leaf == base+64k+63) bumps
//     root; spin until root >= base_root + 8(k+1).
//   - Round-5's end-of-kernel reset removed: it could zero root while other
//     blocks still spun on it (latent hang). Monotonic growth overflows only
//     after ~87k launches — far beyond any bench replay count.
//   - Agent-scope atomics route to a fixed L2 home slice -> coherent across
//     XCDs and across launches. ACQ_REL RMWs + __threadfence release/acquire
//     provide cross-XCD visibility for h/c state.
// Residency: 512 blocks, 64KB LDS + __launch_bounds__(256,2) -> 2 blocks/CU
// (LDS 128<=160KB, VGPR<=256) -> all 512 co-resident; barrier cannot starve.
// ---------------------------------------------------------------------------
__device__ __attribute__((aligned(64))) unsigned g_bar[160]; // leaves i*16, root at 128

__device__ __forceinline__ void gbar(int k, unsigned base_leaf, unsigned base_root) {
    __syncthreads();
    if (threadIdx.x == 0) {
        __threadfence();   // release: push this block's stores agent-wide
        unsigned* leaf = g_bar + ((blockIdx.x & 7) << 4);   // 64B apart
        unsigned* root = g_bar + 128;
        unsigned a = __hip_atomic_fetch_add(leaf, 1u, __ATOMIC_ACQ_REL,
                                            __HIP_MEMORY_SCOPE_AGENT);
        if (a == base_leaf + (unsigned)(k * 64 + 63))
            __hip_atomic_fetch_add(root, 1u, __ATOMIC_ACQ_REL,
                                   __HIP_MEMORY_SCOPE_AGENT);
        const unsigned tgt = base_root + (unsigned)(k * 8 + 8);
        while (__hip_atomic_load(root, __ATOMIC_RELAXED,
                                 __HIP_MEMORY_SCOPE_AGENT) < tgt)
            __builtin_amdgcn_s_sleep(1);
        __threadfence();   // acquire: invalidate stale lines before reads
    }
    __syncthreads();
}

// ---------------------------------------------------------------------------
// LSTM layer phase for hidden unit h == bid. Uses smem[0..5120):
//   wlds = smem[0..4096) as float4[1024], red = smem[4096..5120).
// ---------------------------------------------------------------------------
__device__ __forceinline__ void lstm_phase(
    float* smem, int h,
    const float* __restrict__ emb,
    const int*   __restrict__ xcol,
    const u64*   __restrict__ amax_in,
    const float* __restrict__ inpT,
    const float* __restrict__ hprevT,
    float*       __restrict__ houtT,
    float*       __restrict__ cstate,
    const float* __restrict__ Wih,
    const float* __restrict__ Whh,
    const float* __restrict__ bih,
    const float* __restrict__ bhh,
    int t, int is_layer0)
{
    float4* wlds = (float4*)smem;                           // 16KB
    float (*red)[4][64] = (float (*)[4][64])(smem + 4096);  // 4KB

    const int tid  = threadIdx.x;
    const int wave = __builtin_amdgcn_readfirstlane(tid >> 6);
    const int lane = tid & 63;

    const float4* Wih4 = (const float4*)Wih;
    const float4* Whh4 = (const float4*)Whh;
    #pragma unroll
    for (int i = 0; i < 4; ++i) {
        int g   = i * 256 + tid;
        int s   = g >> 7;
        int off = g & 127;
        const float4* src = (s < 4) ? Wih4 : Whh4;
        wlds[g] = src[(size_t)((s & 3) * Hq + h) * 128 + off];
    }
    __syncthreads();

    const int part = wave >> 1;
    const int kq0  = (wave & 1) << 6;

    float acc0 = 0.f, acc1 = 0.f, acc2 = 0.f, acc3 = 0.f;

    if (part == 0 && is_layer0) {
        int row;
        if (t == 0) {
            row = xcol[lane * Tq];
        } else {
            u64 a = __hip_atomic_load(&amax_in[lane], __ATOMIC_RELAXED,
                                      __HIP_MEMORY_SCOPE_AGENT);
            row = (int)(~(unsigned)a);
        }
        const float4* a4 = (const float4*)(emb + (size_t)row * Eq);
        #pragma unroll 4
        for (int i = 0; i < 64; ++i) {
            float4 a = a4[kq0 + i];
            int kq = kq0 + i;
            float4 w0 = wlds[0 * 128 + kq];
            float4 w1 = wlds[1 * 128 + kq];
            float4 w2 = wlds[2 * 128 + kq];
            float4 w3 = wlds[3 * 128 + kq];
            DOT4(acc0, a, w0); DOT4(acc1, a, w1);
            DOT4(acc2, a, w2); DOT4(acc3, a, w3);
        }
    } else {
        const float4* a4 = (const float4*)(part ? hprevT : inpT);
        #pragma unroll 4
        for (int i = 0; i < 64; ++i) {
            int kq = kq0 + i;
            float4 a = a4[kq * 64 + lane];
            float4 w0 = wlds[(part * 4 + 0) * 128 + kq];
            float4 w1 = wlds[(part * 4 + 1) * 128 + kq];
            float4 w2 = wlds[(part * 4 + 2) * 128 + kq];
            float4 w3 = wlds[(part * 4 + 3) * 128 + kq];
            DOT4(acc0, a, w0); DOT4(acc1, a, w1);
            DOT4(acc2, a, w2); DOT4(acc3, a, w3);
        }
    }

    red[wave][0][lane] = acc0;
    red[wave][1][lane] = acc1;
    red[wave][2][lane] = acc2;
    red[wave][3][lane] = acc3;
    __syncthreads();

    if (wave == 0) {
        float gi = red[0][0][lane] + red[1][0][lane] + red[2][0][lane] + red[3][0][lane]
                 + bih[0 * Hq + h] + bhh[0 * Hq + h];
        float gf = red[0][1][lane] + red[1][1][lane] + red[2][1][lane] + red[3][1][lane]
                 + bih[1 * Hq + h] + bhh[1 * Hq + h];
        float gg = red[0][2][lane] + red[1][2][lane] + red[2][2][lane] + red[3][2][lane]
                 + bih[2 * Hq + h] + bhh[2 * Hq + h];
        float go = red[0][3][lane] + red[1][3][lane] + red[2][3][lane] + red[3][3][lane]
                 + bih[3 * Hq + h] + bhh[3 * Hq + h];
        float cold = cstate[h * 64 + lane];
        float cn = sigmoid_f(gf) * cold + sigmoid_f(gi) * tanhf(gg);
        float hn = sigmoid_f(go) * tanhf(cn);
        cstate[h * 64 + lane] = cn;
        houtT[(h >> 2) * 256 + lane * 4 + (h & 3)] = hn;
    }
}

// ---------------------------------------------------------------------------
// FC staging: one K-chunk (64 k-values) of W (64 rows) and A (h-state),
// XOR bank swizzle, global_load_lds 16B/lane.
// ---------------------------------------------------------------------------
__device__ __forceinline__ void fc_stage_chunk(
    const float* __restrict__ Wfc, const float* __restrict__ hT,
    int v0, int cc, float* dst, int tid, int wave)
{
    const int k0_ = cc * 64;
    #pragma unroll
    for (int it = 0; it < 4; ++it) {
        int g = it * 256 + tid;
        int r = g >> 4, sp = g & 15;
        int gk = k0_ + (((sp ^ (r >> 3)) & 15) << 2);
        gl_lds16(Wfc + (size_t)(v0 + r) * 512 + gk,
                 dst + it * 1024 + wave * 256);
    }
    #pragma unroll
    for (int it = 0; it < 4; ++it) {
        int g = it * 256 + tid;
        int kqr = g >> 6, u = g & 63;
        int b = (u & 56) | ((u & 7) ^ (u >> 3));
        gl_lds16(hT + (size_t)(cc * 16 + kqr) * 256 + b * 4,
                 dst + 4096 + it * 1024 + wave * 256);
    }
}

// ---------------------------------------------------------------------------
// FC head phase, register-blocked 8x8 outer product, vocab tile == bid.
// Uses smem[0..16384) as double buffer [2][8192].
// ---------------------------------------------------------------------------
__device__ __forceinline__ void fc_phase(
    float* smem,
    const float* __restrict__ hT,
    const float* __restrict__ Wfc,
    const float* __restrict__ bfc,
    float*       __restrict__ out,
    u64*         __restrict__ amax,
    int write_out, int tile)
{
    float* lds0 = smem;
    float* lds1 = smem + 8192;
    const int tid  = threadIdx.x;
    const int wave = __builtin_amdgcn_readfirstlane(tid >> 6);
    const int lane = tid & 63;
    const int rgrp = lane >> 3;
    const int bgrp = lane & 7;
    const int v0   = tile * 64;

    float acc[8][8];
    #pragma unroll
    for (int j = 0; j < 8; ++j)
        #pragma unroll
        for (int i = 0; i < 8; ++i) acc[j][i] = 0.f;

    float* cur = lds0;
    float* nxt = lds1;

    fc_stage_chunk(Wfc, hT, v0, 0, cur, tid, wave);
    __syncthreads();                    // drains the DMA before first compute

    for (int c = 0; c < 8; ++c) {
        if (c < 7) fc_stage_chunk(Wfc, hT, v0, c + 1, nxt, tid, wave);

        #pragma unroll
        for (int kq = 0; kq < 4; ++kq) {
            const int sl = wave * 4 + kq;       // logical k-slot 0..15 in chunk
            float4 wv[8], av[8];
            #pragma unroll
            for (int j = 0; j < 8; ++j)
                wv[j] = *(const float4*)(cur + (rgrp * 8 + j) * 64 + (((sl ^ rgrp) & 15) << 2));
            #pragma unroll
            for (int i = 0; i < 8; ++i)
                av[i] = *(const float4*)(cur + 4096 + sl * 256 + ((bgrp * 8 + (i ^ bgrp)) << 2));
            #pragma unroll
            for (int j = 0; j < 8; ++j)
                #pragma unroll
                for (int i = 0; i < 8; ++i)
                    DOT4(acc[j][i], av[i], wv[j]);
        }

        __syncthreads();                // barrier drain completes nxt's DMA too
        float* tmp = cur; cur = nxt; nxt = tmp;
    }

    // ---- cross-wave K reduction into accbuf = lds0 (64x64 fp32) ----
    float* accbuf = lds0;
    for (int w = 0; w < 4; ++w) {
        if (wave == w) {
            #pragma unroll
            for (int j = 0; j < 8; ++j) {
                float* p = accbuf + (rgrp * 8 + j) * 64 + bgrp * 8;
                if (w == 0) {
                    *(float4*)p       = make_float4(acc[j][0], acc[j][1], acc[j][2], acc[j][3]);
                    *(float4*)(p + 4) = make_float4(acc[j][4], acc[j][5], acc[j][6], acc[j][7]);
                } else {
                    float4 a0 = *(const float4*)p;
                    float4 a1 = *(const float4*)(p + 4);
                    a0.x += acc[j][0]; a0.y += acc[j][1]; a0.z += acc[j][2]; a0.w += acc[j][3];
                    a1.x += acc[j][4]; a1.y += acc[j][5]; a1.z += acc[j][6]; a1.w += acc[j][7];
                    *(float4*)p       = a0;
                    *(float4*)(p + 4) = a1;
                }
            }
        }
        __syncthreads();
    }

    // ---- bias + per-batch argmax + (last step) logit store ----
    const int b  = tid & 63;
    const int rq = wave;                // row quarter: 16 rows each
    float best = -__builtin_huge_valf();
    int bi = 0;
    float lg[16];
    #pragma unroll
    for (int n = 0; n < 16; ++n) {
        int r = rq * 16 + n;
        float v = accbuf[r * 64 + b] + bfc[v0 + r];
        lg[n] = v;
        if (v > best) { best = v; bi = v0 + r; }   // '>' keeps smallest index
    }
    u64 pack = ((u64)f2sortable(best) << 32) | (u64)(~(unsigned)bi);

    u64* redm = (u64*)lds1;
    redm[rq * 64 + b] = pack;
    __syncthreads();
    if (rq == 0) {
        u64 m  = redm[b];
        u64 m1 = redm[64 + b];  if (m1 > m) m = m1;
        u64 m2 = redm[128 + b]; if (m2 > m) m = m2;
        u64 m3 = redm[192 + b]; if (m3 > m) m = m3;
        atomicMax(&amax[b], m);
    }

    if (write_out) {
        #pragma unroll
        for (int n = 0; n < 16; ++n)
            out[(size_t)b * Vq + v0 + rq * 16 + n] = lg[n];
    }
}

// ---------------------------------------------------------------------------
// Persistent kernel (PLAIN launch): entire T=256 decode loop in one dispatch.
// 512 blocks x 256 threads, 64KB LDS + __launch_bounds__(256,2)
// -> 2 blocks/CU x 256 CUs = all 512 co-resident, 2 waves/SIMD for latency
// hiding (round-5 fix: 1 block/CU gave 1 wave/SIMD -> VALUBusy 28%).
// Per step: L0 | gbar | L1 (+amax reset) | gbar | FC (bid<500) | gbar.
// ---------------------------------------------------------------------------
__global__ __launch_bounds__(256, 2) void lstm_persistent(
    const int*   __restrict__ x,
    const float* __restrict__ emb,
    const float* __restrict__ Wih,
    const float* __restrict__ Whh,
    const float* __restrict__ bih,
    const float* __restrict__ bhh,
    const float* __restrict__ Wfc,
    const float* __restrict__ bfc,
    float*       __restrict__ out,
    float*       __restrict__ ws)
{
    __shared__ __align__(16) float smem[16384];     // 64KB, phase-aliased

    float* h0T0 = ws;
    float* h0T1 = ws + 32768;
    float* h1T0 = ws + 65536;
    float* h1T1 = ws + 98304;
    float* c0   = ws + 131072;
    float* c1   = ws + 163840;
    u64*   amax = (u64*)(ws + 196608);

    const int bid  = blockIdx.x;
    const int tid  = threadIdx.x;
    const int wave = tid >> 6;
    const int lane = tid & 63;
    const size_t WL = (size_t)4 * Hq * 512;

    // Launch-relative barrier bases (see gbar comment). Thread 0 only.
    unsigned base_leaf = 0, base_root = 0;
    if (tid == 0) {
        base_leaf = __hip_atomic_load(g_bar + ((bid & 7) << 4), __ATOMIC_RELAXED,
                                      __HIP_MEMORY_SCOPE_AGENT) & ~63u;
        base_root = __hip_atomic_load(g_bar + 128, __ATOMIC_RELAXED,
                                      __HIP_MEMORY_SCOPE_AGENT) & ~7u;
    }

    int bk = 0;
    for (int t = 0; t < Tq; ++t) {
        float* h0rd = (t & 1) ? h0T1 : h0T0;
        float* h0wr = (t & 1) ? h0T0 : h0T1;
        float* h1rd = (t & 1) ? h1T1 : h1T0;
        float* h1wr = (t & 1) ? h1T0 : h1T1;

        // ---- layer 0: unit bid ----
        lstm_phase(smem, bid, emb, x, amax, nullptr, h0rd, h0wr, c0,
                   Wih, Whh, bih, bhh, t, 1);
        gbar(bk++, base_leaf, base_root);

        // ---- layer 1 (+ amax reset: L0 already consumed it) ----
        if (bid == 0 && wave == 3) atomicExch(&amax[lane], 0ull);
        lstm_phase(smem, bid, emb, x, amax, h0wr, h1rd, h1wr, c1,
                   Wih + WL, Whh + WL, bih + 4 * Hq, bhh + 4 * Hq, t, 0);
        gbar(bk++, base_leaf, base_root);

        // ---- FC head + argmax: tile bid (500 tiles) ----
        if (bid < 500)
            fc_phase(smem, h1wr, Wfc, bfc, out, amax, (t == Tq - 1) ? 1 : 0, bid);
        gbar(bk++, base_leaf, base_root);
    }
}

extern "C" void kernel_launch(void* const* d_in, const int* in_sizes, int n_in,
                              void* d_out, int out_size, void* d_ws, size_t ws_size,
                              hipStream_t stream)
{
    const int*   x   = (const int*)d_in[0];
    const float* emb = (const float*)d_in[1];
    const float* Wih = (const float*)d_in[2];
    const float* Whh = (const float*)d_in[3];
    const float* bih = (const float*)d_in[4];
    const float* bhh = (const float*)d_in[5];
    const float* Wfc = (const float*)d_in[6];
    const float* bfc = (const float*)d_in[7];
    float* out = (float*)d_out;
    float* ws  = (float*)d_ws;

    // EXACT round-0 workspace footprint (barrier state lives in __device__
    // globals, not the workspace — rounds 3/4 crashed on barrier state
    // placed past this exact boundary).
    hipMemsetAsync(d_ws, 0, 196608 * sizeof(float) + 64 * sizeof(u64), stream);

    lstm_persistent<<<dim3(512), dim3(256), 0, stream>>>(
        x, emb, Wih, Whh, bih, bhh, Wfc, bfc, out, ws);
}

// Round 7
// 34674.548 us; speedup vs baseline: 1.0668x; 1.0668x over previous
//
#include <hip/hip_runtime.h>
#include <stdint.h>

typedef unsigned long long u64;

#define Bq 64
#define Tq 256
#define Hq 512
#define Eq 512
#define Vq 32000

__device__ __forceinline__ float sigmoid_f(float x) { return 1.0f / (1.0f + expf(-x)); }

__device__ __forceinline__ unsigned f2sortable(float f) {
    unsigned u = __float_as_uint(f);
    return (u & 0x80000000u) ? ~u : (u | 0x80000000u);
}

// async global->LDS, 16B per lane; LDS dest is wave-uniform base + lane*16
__device__ __forceinline__ void gl_lds16(const float* g, float* l) {
    __builtin_amdgcn_global_load_lds(
        (const __attribute__((address_space(1))) void*)g,
        (__attribute__((address_space(3))) void*)l, 16, 0, 0);
}

// State layout "stateT": element (k, b) stored at (k>>2)*256 + b*4 + (k&3).
// float4 at word (kq*256 + b*4) == h[b][4kq..4kq+3]  (per-(b,kq) contiguous).

#define DOT4(acc, a, wv) \
    acc = fmaf((a).w, (wv).w, fmaf((a).z, (wv).z, fmaf((a).y, (wv).y, fmaf((a).x, (wv).x, (acc)))))

// ---------------------------------------------------------------------------
// Software grid barrier, MONOTONIC with LAUNCH-RELATIVE targets (no resets).
//   - Counters in __device__ globals (zero .bss at load), NEVER reset.
//   - Entry: base_leaf = leaf & ~63, base_root = root & ~7 (exact: before my
//     arrival my leaf can gain at most 63 in-launch arrivals, root at most 7).
//   - Barrier k: arrive leaf(bid&7); winner bumps root; spin until
//     root >= base_root + 8(k+1).
//   - ACQ_REL RMWs + __threadfence release/acquire for cross-XCD visibility.
// Residency: 512 blocks, 64KB LDS + __launch_bounds__(256,2) -> 2 blocks/CU
// -> all 512 co-resident; barrier cannot starve.
// ROUND-6 LESSON: the (256,2) cap is 128 VGPR; the old FC loop held
// acc[64]+wv[32]+av[32] live -> spill (WRITE_SIZE +71%, VALUBusy 20%).
// FC loop below is restructured to a ~110-VGPR live set.
// ---------------------------------------------------------------------------
__device__ __attribute__((aligned(64))) unsigned g_bar[160]; // leaves i*16, root at 128

__device__ __forceinline__ void gbar(int k, unsigned base_leaf, unsigned base_root) {
    __syncthreads();
    if (threadIdx.x == 0) {
        __threadfence();   // release: push this block's stores agent-wide
        unsigned* leaf = g_bar + ((blockIdx.x & 7) << 4);   // 64B apart
        unsigned* root = g_bar + 128;
        unsigned a = __hip_atomic_fetch_add(leaf, 1u, __ATOMIC_ACQ_REL,
                                            __HIP_MEMORY_SCOPE_AGENT);
        if (a == base_leaf + (unsigned)(k * 64 + 63))
            __hip_atomic_fetch_add(root, 1u, __ATOMIC_ACQ_REL,
                                   __HIP_MEMORY_SCOPE_AGENT);
        const unsigned tgt = base_root + (unsigned)(k * 8 + 8);
        while (__hip_atomic_load(root, __ATOMIC_RELAXED,
                                 __HIP_MEMORY_SCOPE_AGENT) < tgt)
            __builtin_amdgcn_s_sleep(1);
        __threadfence();   // acquire: invalidate stale lines before reads
    }
    __syncthreads();
}

// ---------------------------------------------------------------------------
// LSTM layer phase for hidden unit h == bid. Uses smem[0..5120):
//   wlds = smem[0..4096) as float4[1024], red = smem[4096..5120).
// ---------------------------------------------------------------------------
__device__ __forceinline__ void lstm_phase(
    float* smem, int h,
    const float* __restrict__ emb,
    const int*   __restrict__ xcol,
    const u64*   __restrict__ amax_in,
    const float* __restrict__ inpT,
    const float* __restrict__ hprevT,
    float*       __restrict__ houtT,
    float*       __restrict__ cstate,
    const float* __restrict__ Wih,
    const float* __restrict__ Whh,
    const float* __restrict__ bih,
    const float* __restrict__ bhh,
    int t, int is_layer0)
{
    float4* wlds = (float4*)smem;                           // 16KB
    float (*red)[4][64] = (float (*)[4][64])(smem + 4096);  // 4KB

    const int tid  = threadIdx.x;
    const int wave = __builtin_amdgcn_readfirstlane(tid >> 6);
    const int lane = tid & 63;

    const float4* Wih4 = (const float4*)Wih;
    const float4* Whh4 = (const float4*)Whh;
    #pragma unroll
    for (int i = 0; i < 4; ++i) {
        int g   = i * 256 + tid;
        int s   = g >> 7;
        int off = g & 127;
        const float4* src = (s < 4) ? Wih4 : Whh4;
        wlds[g] = src[(size_t)((s & 3) * Hq + h) * 128 + off];
    }
    __syncthreads();

    const int part = wave >> 1;
    const int kq0  = (wave & 1) << 6;

    float acc0 = 0.f, acc1 = 0.f, acc2 = 0.f, acc3 = 0.f;

    if (part == 0 && is_layer0) {
        int row;
        if (t == 0) {
            row = xcol[lane * Tq];
        } else {
            u64 a = __hip_atomic_load(&amax_in[lane], __ATOMIC_RELAXED,
                                      __HIP_MEMORY_SCOPE_AGENT);
            row = (int)(~(unsigned)a);
        }
        const float4* a4 = (const float4*)(emb + (size_t)row * Eq);
        #pragma unroll 4
        for (int i = 0; i < 64; ++i) {
            float4 a = a4[kq0 + i];
            int kq = kq0 + i;
            float4 w0 = wlds[0 * 128 + kq];
            float4 w1 = wlds[1 * 128 + kq];
            float4 w2 = wlds[2 * 128 + kq];
            float4 w3 = wlds[3 * 128 + kq];
            DOT4(acc0, a, w0); DOT4(acc1, a, w1);
            DOT4(acc2, a, w2); DOT4(acc3, a, w3);
        }
    } else {
        const float4* a4 = (const float4*)(part ? hprevT : inpT);
        #pragma unroll 4
        for (int i = 0; i < 64; ++i) {
            int kq = kq0 + i;
            float4 a = a4[kq * 64 + lane];
            float4 w0 = wlds[(part * 4 + 0) * 128 + kq];
            float4 w1 = wlds[(part * 4 + 1) * 128 + kq];
            float4 w2 = wlds[(part * 4 + 2) * 128 + kq];
            float4 w3 = wlds[(part * 4 + 3) * 128 + kq];
            DOT4(acc0, a, w0); DOT4(acc1, a, w1);
            DOT4(acc2, a, w2); DOT4(acc3, a, w3);
        }
    }

    red[wave][0][lane] = acc0;
    red[wave][1][lane] = acc1;
    red[wave][2][lane] = acc2;
    red[wave][3][lane] = acc3;
    __syncthreads();

    if (wave == 0) {
        float gi = red[0][0][lane] + red[1][0][lane] + red[2][0][lane] + red[3][0][lane]
                 + bih[0 * Hq + h] + bhh[0 * Hq + h];
        float gf = red[0][1][lane] + red[1][1][lane] + red[2][1][lane] + red[3][1][lane]
                 + bih[1 * Hq + h] + bhh[1 * Hq + h];
        float gg = red[0][2][lane] + red[1][2][lane] + red[2][2][lane] + red[3][2][lane]
                 + bih[2 * Hq + h] + bhh[2 * Hq + h];
        float go = red[0][3][lane] + red[1][3][lane] + red[2][3][lane] + red[3][3][lane]
                 + bih[3 * Hq + h] + bhh[3 * Hq + h];
        float cold = cstate[h * 64 + lane];
        float cn = sigmoid_f(gf) * cold + sigmoid_f(gi) * tanhf(gg);
        float hn = sigmoid_f(go) * tanhf(cn);
        cstate[h * 64 + lane] = cn;
        houtT[(h >> 2) * 256 + lane * 4 + (h & 3)] = hn;
    }
}

// ---------------------------------------------------------------------------
// FC staging: one K-chunk (64 k-values) of W (64 rows) and A (h-state),
// XOR bank swizzle, global_load_lds 16B/lane.
// ---------------------------------------------------------------------------
__device__ __forceinline__ void fc_stage_chunk(
    const float* __restrict__ Wfc, const float* __restrict__ hT,
    int v0, int cc, float* dst, int tid, int wave)
{
    const int k0_ = cc * 64;
    #pragma unroll
    for (int it = 0; it < 4; ++it) {
        int g = it * 256 + tid;
        int r = g >> 4, sp = g & 15;
        int gk = k0_ + (((sp ^ (r >> 3)) & 15) << 2);
        gl_lds16(Wfc + (size_t)(v0 + r) * 512 + gk,
                 dst + it * 1024 + wave * 256);
    }
    #pragma unroll
    for (int it = 0; it < 4; ++it) {
        int g = it * 256 + tid;
        int kqr = g >> 6, u = g & 63;
        int b = (u & 56) | ((u & 7) ^ (u >> 3));
        gl_lds16(hT + (size_t)(cc * 16 + kqr) * 256 + b * 4,
                 dst + 4096 + it * 1024 + wave * 256);
    }
}

// ---------------------------------------------------------------------------
// FC head phase, register-blocked 8x8 outer product, vocab tile == bid.
// Uses smem[0..16384) as double buffer [2][8192].
// Inner loop restructured for the 128-VGPR cap (round-6 spill fix):
// av[8] loaded once per k-slot (32 VGPR), wv streamed one at a time
// (4 VGPR live) -> structural live set acc 64 + av 32 + wv 4 + addrs ~ 110.
// ---------------------------------------------------------------------------
__device__ __forceinline__ void fc_phase(
    float* smem,
    const float* __restrict__ hT,
    const float* __restrict__ Wfc,
    const float* __restrict__ bfc,
    float*       __restrict__ out,
    u64*         __restrict__ amax,
    int write_out, int tile)
{
    float* lds0 = smem;
    float* lds1 = smem + 8192;
    const int tid  = threadIdx.x;
    const int wave = __builtin_amdgcn_readfirstlane(tid >> 6);
    const int lane = tid & 63;
    const int rgrp = lane >> 3;
    const int bgrp = lane & 7;
    const int v0   = tile * 64;

    float acc[8][8];
    #pragma unroll
    for (int j = 0; j < 8; ++j)
        #pragma unroll
        for (int i = 0; i < 8; ++i) acc[j][i] = 0.f;

    float* cur = lds0;
    float* nxt = lds1;

    fc_stage_chunk(Wfc, hT, v0, 0, cur, tid, wave);
    __syncthreads();                    // drains the DMA before first compute

    for (int c = 0; c < 8; ++c) {
        if (c < 7) fc_stage_chunk(Wfc, hT, v0, c + 1, nxt, tid, wave);

        #pragma unroll
        for (int kq = 0; kq < 4; ++kq) {
            const int sl = wave * 4 + kq;       // logical k-slot 0..15 in chunk
            float4 av[8];
            #pragma unroll
            for (int i = 0; i < 8; ++i)
                av[i] = *(const float4*)(cur + 4096 + sl * 256 + ((bgrp * 8 + (i ^ bgrp)) << 2));
            #pragma unroll
            for (int j = 0; j < 8; ++j) {
                float4 wv = *(const float4*)(cur + (rgrp * 8 + j) * 64 + (((sl ^ rgrp) & 15) << 2));
                #pragma unroll
                for (int i = 0; i < 8; ++i)
                    DOT4(acc[j][i], av[i], wv);
            }
        }

        __syncthreads();                // barrier drain completes nxt's DMA too
        float* tmp = cur; cur = nxt; nxt = tmp;
    }

    // ---- cross-wave K reduction into accbuf = lds0 (64x64 fp32) ----
    float* accbuf = lds0;
    for (int w = 0; w < 4; ++w) {
        if (wave == w) {
            #pragma unroll
            for (int j = 0; j < 8; ++j) {
                float* p = accbuf + (rgrp * 8 + j) * 64 + bgrp * 8;
                if (w == 0) {
                    *(float4*)p       = make_float4(acc[j][0], acc[j][1], acc[j][2], acc[j][3]);
                    *(float4*)(p + 4) = make_float4(acc[j][4], acc[j][5], acc[j][6], acc[j][7]);
                } else {
                    float4 a0 = *(const float4*)p;
                    float4 a1 = *(const float4*)(p + 4);
                    a0.x += acc[j][0]; a0.y += acc[j][1]; a0.z += acc[j][2]; a0.w += acc[j][3];
                    a1.x += acc[j][4]; a1.y += acc[j][5]; a1.z += acc[j][6]; a1.w += acc[j][7];
                    *(float4*)p       = a0;
                    *(float4*)(p + 4) = a1;
                }
            }
        }
        __syncthreads();
    }

    // ---- bias + per-batch argmax + (last step) logit store ----
    const int b  = tid & 63;
    const int rq = wave;                // row quarter: 16 rows each
    float best = -__builtin_huge_valf();
    int bi = 0;
    float lg[16];
    #pragma unroll
    for (int n = 0; n < 16; ++n) {
        int r = rq * 16 + n;
        float v = accbuf[r * 64 + b] + bfc[v0 + r];
        lg[n] = v;
        if (v > best) { best = v; bi = v0 + r; }   // '>' keeps smallest index
    }
    u64 pack = ((u64)f2sortable(best) << 32) | (u64)(~(unsigned)bi);

    u64* redm = (u64*)lds1;
    redm[rq * 64 + b] = pack;
    __syncthreads();
    if (rq == 0) {
        u64 m  = redm[b];
        u64 m1 = redm[64 + b];  if (m1 > m) m = m1;
        u64 m2 = redm[128 + b]; if (m2 > m) m = m2;
        u64 m3 = redm[192 + b]; if (m3 > m) m = m3;
        atomicMax(&amax[b], m);
    }

    if (write_out) {
        #pragma unroll
        for (int n = 0; n < 16; ++n)
            out[(size_t)b * Vq + v0 + rq * 16 + n] = lg[n];
    }
}

// ---------------------------------------------------------------------------
// Persistent kernel (PLAIN launch): entire T=256 decode loop in one dispatch.
// 512 blocks x 256 threads, 64KB LDS + __launch_bounds__(256,2)
// -> 2 blocks/CU x 256 CUs = all 512 co-resident, 2 waves/SIMD.
// Per step: L0 | gbar | L1 (+amax reset) | gbar | FC (bid<500) | gbar.
// ---------------------------------------------------------------------------
__global__ __launch_bounds__(256, 2) void lstm_persistent(
    const int*   __restrict__ x,
    const float* __restrict__ emb,
    const float* __restrict__ Wih,
    const float* __restrict__ Whh,
    const float* __restrict__ bih,
    const float* __restrict__ bhh,
    const float* __restrict__ Wfc,
    const float* __restrict__ bfc,
    float*       __restrict__ out,
    float*       __restrict__ ws)
{
    __shared__ __align__(16) float smem[16384];     // 64KB, phase-aliased

    float* h0T0 = ws;
    float* h0T1 = ws + 32768;
    float* h1T0 = ws + 65536;
    float* h1T1 = ws + 98304;
    float* c0   = ws + 131072;
    float* c1   = ws + 163840;
    u64*   amax = (u64*)(ws + 196608);

    const int bid  = blockIdx.x;
    const int tid  = threadIdx.x;
    const int wave = tid >> 6;
    const int lane = tid & 63;
    const size_t WL = (size_t)4 * Hq * 512;

    // Launch-relative barrier bases (see gbar comment). Thread 0 only.
    unsigned base_leaf = 0, base_root = 0;
    if (tid == 0) {
        base_leaf = __hip_atomic_load(g_bar + ((bid & 7) << 4), __ATOMIC_RELAXED,
                                      __HIP_MEMORY_SCOPE_AGENT) & ~63u;
        base_root = __hip_atomic_load(g_bar + 128, __ATOMIC_RELAXED,
                                      __HIP_MEMORY_SCOPE_AGENT) & ~7u;
    }

    int bk = 0;
    for (int t = 0; t < Tq; ++t) {
        float* h0rd = (t & 1) ? h0T1 : h0T0;
        float* h0wr = (t & 1) ? h0T0 : h0T1;
        float* h1rd = (t & 1) ? h1T1 : h1T0;
        float* h1wr = (t & 1) ? h1T0 : h1T1;

        // ---- layer 0: unit bid ----
        lstm_phase(smem, bid, emb, x, amax, nullptr, h0rd, h0wr, c0,
                   Wih, Whh, bih, bhh, t, 1);
        gbar(bk++, base_leaf, base_root);

        // ---- layer 1 (+ amax reset: L0 already consumed it) ----
        if (bid == 0 && wave == 3) atomicExch(&amax[lane], 0ull);
        lstm_phase(smem, bid, emb, x, amax, h0wr, h1rd, h1wr, c1,
                   Wih + WL, Whh + WL, bih + 4 * Hq, bhh + 4 * Hq, t, 0);
        gbar(bk++, base_leaf, base_root);

        // ---- FC head + argmax: tile bid (500 tiles) ----
        if (bid < 500)
            fc_phase(smem, h1wr, Wfc, bfc, out, amax, (t == Tq - 1) ? 1 : 0, bid);
        gbar(bk++, base_leaf, base_root);
    }
}

extern "C" void kernel_launch(void* const* d_in, const int* in_sizes, int n_in,
                              void* d_out, int out_size, void* d_ws, size_t ws_size,
                              hipStream_t stream)
{
    const int*   x   = (const int*)d_in[0];
    const float* emb = (const float*)d_in[1];
    const float* Wih = (const float*)d_in[2];
    const float* Whh = (const float*)d_in[3];
    const float* bih = (const float*)d_in[4];
    const float* bhh = (const float*)d_in[5];
    const float* Wfc = (const float*)d_in[6];
    const float* bfc = (const float*)d_in[7];
    float* out = (float*)d_out;
    float* ws  = (float*)d_ws;

    // EXACT round-0 workspace footprint (barrier state lives in __device__
    // globals, not the workspace).
    hipMemsetAsync(d_ws, 0, 196608 * sizeof(float) + 64 * sizeof(u64), stream);

    lstm_persistent<<<dim3(512), dim3(256), 0, stream>>>(
        x, emb, Wih, Whh, bih, bhh, Wfc, bfc, out, ws);
}

// Round 8
// 21161.349 us; speedup vs baseline: 1.7480x; 1.6386x over previous
//
#include <hip/hip_runtime.h>
#include <stdint.h>

typedef unsigned long long u64;

#define Bq 64
#define Tq 256
#define Hq 512
#define Eq 512
#define Vq 32000

__device__ __forceinline__ float sigmoid_f(float x) { return 1.0f / (1.0f + expf(-x)); }

__device__ __forceinline__ unsigned f2sortable(float f) {
    unsigned u = __float_as_uint(f);
    return (u & 0x80000000u) ? ~u : (u | 0x80000000u);
}

// async global->LDS, 16B per lane; LDS dest is wave-uniform base + lane*16
__device__ __forceinline__ void gl_lds16(const float* g, float* l) {
    __builtin_amdgcn_global_load_lds(
        (const __attribute__((address_space(1))) void*)g,
        (__attribute__((address_space(3))) void*)l, 16, 0, 0);
}

// State layout "stateT": element (k, b) stored at (k>>2)*256 + b*4 + (k&3).
// float4 at word (kq*256 + b*4) == h[b][4kq..4kq+3]  (per-(b,kq) contiguous).

#define DOT4(acc, a, wv) \
    acc = fmaf((a).w, (wv).w, fmaf((a).z, (wv).z, fmaf((a).y, (wv).y, fmaf((a).x, (wv).x, (acc)))))

// ---------------------------------------------------------------------------
// LSTM layer kernel: one block per hidden unit.
// ---------------------------------------------------------------------------
__global__ __launch_bounds__(256) void lstm_layer_kernel(
    const float* __restrict__ emb,
    const int*   __restrict__ xcol,
    const u64*   __restrict__ amax_in,
    const float* __restrict__ inpT,
    const float* __restrict__ hprevT,
    float*       __restrict__ houtT,
    float*       __restrict__ cstate,
    const float* __restrict__ Wih,
    const float* __restrict__ Whh,
    const float* __restrict__ bih,
    const float* __restrict__ bhh,
    u64*         __restrict__ amax_reset,
    int t, int is_layer0)
{
    __shared__ float4 wlds[1024];             // 8 rows x 128 f4 = 16KB
    const int h    = blockIdx.x;
    const int tid  = threadIdx.x;
    const int wave = __builtin_amdgcn_readfirstlane(tid >> 6);
    const int lane = tid & 63;

    if (amax_reset && blockIdx.x == 0 && wave == 3) amax_reset[lane] = 0;

    const float4* Wih4 = (const float4*)Wih;
    const float4* Whh4 = (const float4*)Whh;
    #pragma unroll
    for (int i = 0; i < 4; ++i) {
        int g   = i * 256 + tid;
        int s   = g >> 7;
        int off = g & 127;
        const float4* src = (s < 4) ? Wih4 : Whh4;
        wlds[g] = src[(size_t)((s & 3) * Hq + h) * 128 + off];
    }
    __syncthreads();

    const int part = wave >> 1;
    const int kq0  = (wave & 1) << 6;

    float acc0 = 0.f, acc1 = 0.f, acc2 = 0.f, acc3 = 0.f;

    if (part == 0 && is_layer0) {
        int row = (t == 0) ? xcol[lane * Tq] : (int)(~(unsigned)amax_in[lane]);
        const float4* a4 = (const float4*)(emb + (size_t)row * Eq);
        #pragma unroll 4
        for (int i = 0; i < 64; ++i) {
            float4 a = a4[kq0 + i];
            int kq = kq0 + i;
            float4 w0 = wlds[0 * 128 + kq];
            float4 w1 = wlds[1 * 128 + kq];
            float4 w2 = wlds[2 * 128 + kq];
            float4 w3 = wlds[3 * 128 + kq];
            DOT4(acc0, a, w0); DOT4(acc1, a, w1);
            DOT4(acc2, a, w2); DOT4(acc3, a, w3);
        }
    } else {
        const float4* a4 = (const float4*)(part ? hprevT : inpT);
        #pragma unroll 4
        for (int i = 0; i < 64; ++i) {
            int kq = kq0 + i;
            float4 a = a4[kq * 64 + lane];
            float4 w0 = wlds[(part * 4 + 0) * 128 + kq];
            float4 w1 = wlds[(part * 4 + 1) * 128 + kq];
            float4 w2 = wlds[(part * 4 + 2) * 128 + kq];
            float4 w3 = wlds[(part * 4 + 3) * 128 + kq];
            DOT4(acc0, a, w0); DOT4(acc1, a, w1);
            DOT4(acc2, a, w2); DOT4(acc3, a, w3);
        }
    }

    __shared__ float red[4][4][64];
    red[wave][0][lane] = acc0;
    red[wave][1][lane] = acc1;
    red[wave][2][lane] = acc2;
    red[wave][3][lane] = acc3;
    __syncthreads();

    if (wave == 0) {
        float gi = red[0][0][lane] + red[1][0][lane] + red[2][0][lane] + red[3][0][lane]
                 + bih[0 * Hq + h] + bhh[0 * Hq + h];
        float gf = red[0][1][lane] + red[1][1][lane] + red[2][1][lane] + red[3][1][lane]
                 + bih[1 * Hq + h] + bhh[1 * Hq + h];
        float gg = red[0][2][lane] + red[1][2][lane] + red[2][2][lane] + red[3][2][lane]
                 + bih[2 * Hq + h] + bhh[2 * Hq + h];
        float go = red[0][3][lane] + red[1][3][lane] + red[2][3][lane] + red[3][3][lane]
                 + bih[3 * Hq + h] + bhh[3 * Hq + h];
        float cold = cstate[h * 64 + lane];
        float cn = sigmoid_f(gf) * cold + sigmoid_f(gi) * tanhf(gg);
        float hn = sigmoid_f(go) * tanhf(cn);
        cstate[h * 64 + lane] = cn;
        houtT[(h >> 2) * 256 + lane * 4 + (h & 3)] = hn;
    }
}

// ---------------------------------------------------------------------------
// FC head, register-blocked 8x8 outer product.
// Block: 64 vocab rows x 64 batches, K=512 split 4-way across waves (128 each),
// K chunked by 64, double-buffered global_load_lds staging with XOR bank
// swizzle (slot s stored at s^group so 8-way broadcast reads span 32 banks).
// lane = rgrp(8 rows-of-8) x bgrp(8 batches-of-8); 64 fp32 accumulators.
// ---------------------------------------------------------------------------
__global__ __launch_bounds__(256) void fc_kernel(
    const float* __restrict__ hT,       // h1 state, stateT layout
    const float* __restrict__ Wfc,      // (V, 512)
    const float* __restrict__ bfc,      // (V)
    float*       __restrict__ out,      // (B, V), written on last step only
    u64*         __restrict__ amax,     // packed argmax accumulator
    int write_out)
{
    __shared__ float lds[2][8192];      // [buf][ W 4096 | A 4096 ] words, 64KB
    const int tid  = threadIdx.x;
    const int wave = __builtin_amdgcn_readfirstlane(tid >> 6);
    const int lane = tid & 63;
    const int rgrp = lane >> 3;         // row group (8 rows each)
    const int bgrp = lane & 7;          // batch group (8 batches each)
    const int v0   = blockIdx.x * 64;

    float acc[8][8];
    #pragma unroll
    for (int j = 0; j < 8; ++j)
        #pragma unroll
        for (int i = 0; i < 8; ++i) acc[j][i] = 0.f;

#define STAGE_CHUNK(cc, dst)                                                  \
    {                                                                         \
        const int k0_ = (cc) * 64;                                            \
        _Pragma("unroll")                                                     \
        for (int it = 0; it < 4; ++it) {                                      \
            int g = it * 256 + tid;                                           \
            int r = g >> 4, sp = g & 15;                                      \
            int gk = k0_ + (((sp ^ (r >> 3)) & 15) << 2);                     \
            gl_lds16(Wfc + (size_t)(v0 + r) * 512 + gk,                       \
                     (dst) + it * 1024 + wave * 256);                         \
        }                                                                     \
        _Pragma("unroll")                                                     \
        for (int it = 0; it < 4; ++it) {                                      \
            int g = it * 256 + tid;                                           \
            int kqr = g >> 6, u = g & 63;                                     \
            int b = (u & 56) | ((u & 7) ^ (u >> 3));                          \
            gl_lds16(hT + (size_t)((cc) * 16 + kqr) * 256 + b * 4,            \
                     (dst) + 4096 + it * 1024 + wave * 256);                  \
        }                                                                     \
    }

    float* cur = lds[0];
    float* nxt = lds[1];

    STAGE_CHUNK(0, cur)
    __syncthreads();                    // drains the DMA before first compute

    for (int c = 0; c < 8; ++c) {
        if (c < 7) STAGE_CHUNK(c + 1, nxt)

        #pragma unroll
        for (int kq = 0; kq < 4; ++kq) {
            const int sl = wave * 4 + kq;       // logical k-slot 0..15 in chunk
            float4 wv[8], av[8];
            #pragma unroll
            for (int j = 0; j < 8; ++j)
                wv[j] = *(const float4*)(cur + (rgrp * 8 + j) * 64 + (((sl ^ rgrp) & 15) << 2));
            #pragma unroll
            for (int i = 0; i < 8; ++i)
                av[i] = *(const float4*)(cur + 4096 + sl * 256 + ((bgrp * 8 + (i ^ bgrp)) << 2));
            #pragma unroll
            for (int j = 0; j < 8; ++j)
                #pragma unroll
                for (int i = 0; i < 8; ++i)
                    DOT4(acc[j][i], av[i], wv[j]);
        }

        __syncthreads();                // barrier drain completes nxt's DMA too
        float* tmp = cur; cur = nxt; nxt = tmp;
    }

    // ---- cross-wave K reduction into accbuf = lds[0] (64x64 fp32) ----
    float* accbuf = lds[0];
    for (int w = 0; w < 4; ++w) {
        if (wave == w) {
            #pragma unroll
            for (int j = 0; j < 8; ++j) {
                float* p = accbuf + (rgrp * 8 + j) * 64 + bgrp * 8;
                if (w == 0) {
                    *(float4*)p       = make_float4(acc[j][0], acc[j][1], acc[j][2], acc[j][3]);
                    *(float4*)(p + 4) = make_float4(acc[j][4], acc[j][5], acc[j][6], acc[j][7]);
                } else {
                    float4 a0 = *(const float4*)p;
                    float4 a1 = *(const float4*)(p + 4);
                    a0.x += acc[j][0]; a0.y += acc[j][1]; a0.z += acc[j][2]; a0.w += acc[j][3];
                    a1.x += acc[j][4]; a1.y += acc[j][5]; a1.z += acc[j][6]; a1.w += acc[j][7];
                    *(float4*)p       = a0;
                    *(float4*)(p + 4) = a1;
                }
            }
        }
        __syncthreads();
    }

    // ---- bias + per-batch argmax + (last step) logit store ----
    const int b  = tid & 63;
    const int rq = wave;                // row quarter: 16 rows each
    float best = -__builtin_huge_valf();
    int bi = 0;
    float lg[16];
    #pragma unroll
    for (int n = 0; n < 16; ++n) {
        int r = rq * 16 + n;
        float v = accbuf[r * 64 + b] + bfc[v0 + r];
        lg[n] = v;
        if (v > best) { best = v; bi = v0 + r; }   // '>' keeps smallest index
    }
    u64 pack = ((u64)f2sortable(best) << 32) | (u64)(~(unsigned)bi);

    u64* redm = (u64*)lds[1];
    redm[rq * 64 + b] = pack;
    __syncthreads();
    if (rq == 0) {
        u64 m  = redm[b];
        u64 m1 = redm[64 + b];  if (m1 > m) m = m1;
        u64 m2 = redm[128 + b]; if (m2 > m) m = m2;
        u64 m3 = redm[192 + b]; if (m3 > m) m = m3;
        atomicMax(&amax[b], m);
    }

    if (write_out) {
        #pragma unroll
        for (int n = 0; n < 16; ++n)
            out[(size_t)b * Vq + v0 + rq * 16 + n] = lg[n];
    }
}

extern "C" void kernel_launch(void* const* d_in, const int* in_sizes, int n_in,
                              void* d_out, int out_size, void* d_ws, size_t ws_size,
                              hipStream_t stream)
{
    const int*   x   = (const int*)d_in[0];
    const float* emb = (const float*)d_in[1];
    const float* Wih = (const float*)d_in[2];
    const float* Whh = (const float*)d_in[3];
    const float* bih = (const float*)d_in[4];
    const float* bhh = (const float*)d_in[5];
    const float* Wfc = (const float*)d_in[6];
    const float* bfc = (const float*)d_in[7];
    float* out = (float*)d_out;

    float* ws = (float*)d_ws;
    float* h0T[2] = { ws,          ws + 32768 };
    float* h1T[2] = { ws + 65536,  ws + 98304 };
    float* c0 = ws + 131072;
    float* c1 = ws + 163840;
    u64* amax = (u64*)(ws + 196608);

    hipMemsetAsync(d_ws, 0, 196608 * sizeof(float) + 64 * sizeof(u64), stream);

    const size_t WL = (size_t)4 * Hq * 512;
    for (int t = 0; t < Tq; ++t) {
        int rd = t & 1, wr = (t + 1) & 1;
        lstm_layer_kernel<<<512, 256, 0, stream>>>(
            emb, x, amax, nullptr, h0T[rd], h0T[wr], c0,
            Wih, Whh, bih, bhh,
            nullptr, t, 1);
        lstm_layer_kernel<<<512, 256, 0, stream>>>(
            emb, x, amax, h0T[wr], h1T[rd], h1T[wr], c1,
            Wih + WL, Whh + WL, bih + 4 * Hq, bhh + 4 * Hq,
            amax, t, 0);
        fc_kernel<<<500, 256, 0, stream>>>(
            h1T[wr], Wfc, bfc, out, amax, (t == Tq - 1) ? 1 : 0);
    }
}